// Round 17
// baseline (293.718 us; speedup 1.0000x reference)
//
#include <hip/hip_runtime.h>
#include <hip/hip_bf16.h>

typedef __attribute__((ext_vector_type(8))) short s8v;   // 8 x bf16
typedef __attribute__((ext_vector_type(4))) float f32x4; // MFMA acc

__device__ __forceinline__ float sigf(float x) { return 1.0f / (1.0f + __expf(-x)); }
__device__ __forceinline__ float tanh_fast(float x) { return 1.0f - 2.0f / (1.0f + __expf(2.0f * x)); }
__device__ __forceinline__ ushort f2bf(float f) {
    union { __hip_bfloat16 b; ushort u; } v; v.b = __float2bfloat16(f); return v.u;
}

// ---------------- prepass (same as R16) ----------------
__global__ __launch_bounds__(256) void prepass(
    const float* __restrict__ emb,
    const float* __restrict__ Wih, const float* __restrict__ Whh,
    const float* __restrict__ bih, const float* __restrict__ bhh,
    ushort* __restrict__ Bpack, float4* __restrict__ PX4, float4* __restrict__ Wcol4,
    ushort* __restrict__ HLEAF, float* __restrict__ CLEAF)
{
    const int bx = blockIdx.x;
    const int tid = threadIdx.x;
    if (bx < 64) {
        const int gid = bx * 256 + tid;     // (ty, j)
        const int ty = gid >> 7;
        const int j  = gid & 127;
        const float* e = emb + (size_t)ty * 128;
        float d[4];
        #pragma unroll
        for (int g = 0; g < 4; ++g) {
            const int row = g * 256 + j;
            const float* wr = Wih + (size_t)row * 128;
            float acc = bih[row] + bhh[row];
            #pragma unroll 8
            for (int k = 0; k < 128; k += 4) {
                float4 ev = *(const float4*)(e + k);
                float4 wv = *(const float4*)(wr + k);
                acc = fmaf(ev.x, wv.x, acc); acc = fmaf(ev.y, wv.y, acc);
                acc = fmaf(ev.z, wv.z, acc); acc = fmaf(ev.w, wv.w, acc);
            }
            d[g] = acc;
        }
        PX4[gid] = make_float4(d[0], d[1], d[2], d[3]);
        const float cn = sigf(d[0]) * tanh_fast(d[2]);
        CLEAF[gid] = cn;
        HLEAF[gid] = f2bf(sigf(d[3]) * tanh_fast(cn));
        if (ty == 0)
            Wcol4[j] = make_float4(Wih[(size_t)j * 128 + 127],
                                   Wih[(size_t)(256 + j) * 128 + 127],
                                   Wih[(size_t)(512 + j) * 128 + 127],
                                   Wih[(size_t)(768 + j) * 128 + 127]);
    } else {
        const int gid = (bx - 64) * 256 + tid;   // Bpack (Whh only, K=256)
        const int nl  = gid & 127;
        const int seg = (gid >> 7) & 3;
        const int rest = gid >> 9;
        const int kk = rest & 7;
        const int bn = rest >> 3;
        const int g  = (nl >> 4) & 3;
        const int j  = bn * 32 + ((nl >> 6) << 4) + (nl & 15);
        const int row = g * 256 + j;
        const int k = kk * 32 + seg * 8;
        const float* src = Whh + (size_t)row * 256 + k;
        float4 w0 = *(const float4*)(src);
        float4 w1 = *(const float4*)(src + 4);
        ushort o[8] = { f2bf(w0.x), f2bf(w0.y), f2bf(w0.z), f2bf(w0.w),
                        f2bf(w1.x), f2bf(w1.y), f2bf(w1.z), f2bf(w1.w) };
        *(s8v*)(Bpack + (size_t)gid * 8) = *(const s8v*)o;
    }
}

// ---------------- stage helpers ----------------
// M=64 GEMM (one 64-row pass), children h/c from GLOBAL, writes LDS hO/cO.
__device__ __forceinline__ void gemm64_global(
    int rowbase, int nD, int startD,
    const int* __restrict__ nt, const float* __restrict__ na,
    const ushort* __restrict__ h_in, const float* __restrict__ c_in,
    const ushort* __restrict__ Bpack, const float4* __restrict__ PX4,
    const float4* __restrict__ Wcol4, float e1, float e2,
    ushort (*hO)[136], float (*cO)[132])
{
    const int tid  = threadIdx.x;
    const int lane = tid & 63;
    const int wave = tid >> 6;
    const int wm2 = wave >> 2;
    const int bn  = wave & 3;
    const int lc = lane & 15, seg = lane >> 4;
    const int koff = seg * 8;

    const ushort* ph[2][2];
    #pragma unroll
    for (int mi = 0; mi < 2; ++mi) {
        int mloc = wm2 * 32 + mi * 16 + lc;
        int dg = rowbase + mloc;
        int dgc = dg < nD ? dg : nD - 1;
        ph[mi][0] = h_in + (size_t)(2 * dgc) * 128 + koff;
        ph[mi][1] = h_in + (size_t)(2 * dgc + 1) * 128 + koff;
    }
    const ushort* pb = Bpack + (size_t)bn * 32768 + (size_t)seg * 1024
                             + (size_t)lc * 8;

    f32x4 acc[2][8];
    #pragma unroll
    for (int mi = 0; mi < 2; ++mi)
        #pragma unroll
        for (int f = 0; f < 8; ++f) acc[mi][f] = (f32x4){0.f, 0.f, 0.f, 0.f};

    #pragma unroll
    for (int kk = 0; kk < 8; ++kk) {
        const int hi = kk >> 2, off = (kk & 3) * 32;
        s8v a0 = *(const s8v*)(ph[0][hi] + off);
        s8v a1 = *(const s8v*)(ph[1][hi] + off);
        #pragma unroll
        for (int f = 0; f < 8; ++f) {
            s8v bb = *(const s8v*)(pb + (size_t)kk * 4096 + f * 128);
            acc[0][f] = __builtin_amdgcn_mfma_f32_16x16x32_bf16(a0, bb, acc[0][f], 0, 0, 0);
            acc[1][f] = __builtin_amdgcn_mfma_f32_16x16x32_bf16(a1, bb, acc[1][f], 0, 0, 0);
        }
    }
    #pragma unroll
    for (int bh = 0; bh < 2; ++bh) {
        const int j = bn * 32 + bh * 16 + lc;
        const float4 wc = Wcol4[j];
        #pragma unroll
        for (int mi = 0; mi < 2; ++mi) {
            #pragma unroll
            for (int r = 0; r < 4; ++r) {
                const int mloc = wm2 * 32 + mi * 16 + seg * 4 + r;
                const int dg = rowbase + mloc;
                if (dg < nD) {
                    const int node = startD + dg;
                    const int ty = nt[node];
                    const float corr = (ty == 1) ? (na[node] - e1)
                                     : ((ty == 2) ? (na[node] - e2) : 0.0f);
                    const float4 px = PX4[(size_t)ty * 128 + j];
                    const float gi = acc[mi][bh * 4 + 0][r] + px.x + corr * wc.x;
                    const float gf = acc[mi][bh * 4 + 1][r] + px.y + corr * wc.y;
                    const float gg = acc[mi][bh * 4 + 2][r] + px.z + corr * wc.z;
                    const float go = acc[mi][bh * 4 + 3][r] + px.w + corr * wc.w;
                    const float c0 = c_in[(size_t)dg * 128 + j];
                    const float cn = sigf(gf) * c0 + sigf(gi) * tanh_fast(gg);
                    const float hn = sigf(go) * tanh_fast(cn);
                    hO[mloc][j] = f2bf(hn);
                    if (!(mloc & 1)) cO[mloc >> 1][j] = cn;
                }
            }
        }
    }
}

// M=64 GEMM, children h/c from LDS (hIn 128 rows, cIn 64 rows), writes LDS hO/cO.
__device__ __forceinline__ void gemm64_lds(
    int b, int nM, int startM,
    const int* __restrict__ nt, const float* __restrict__ na,
    const ushort (*hIn)[136], const float (*cIn)[132],
    const ushort* __restrict__ Bpack, const float4* __restrict__ PX4,
    const float4* __restrict__ Wcol4, float e1, float e2,
    ushort (*hO)[136], float (*cO)[132])
{
    const int tid  = threadIdx.x;
    const int lane = tid & 63;
    const int wave = tid >> 6;
    const int wm2 = wave >> 2;
    const int bn  = wave & 3;
    const int lc = lane & 15, seg = lane >> 4;
    const int koff = seg * 8;
    int nMloc = nM - 64 * b; if (nMloc > 64) nMloc = 64;

    int mlc[2];
    #pragma unroll
    for (int mi = 0; mi < 2; ++mi) {
        int mloc = wm2 * 32 + mi * 16 + lc;
        mlc[mi] = mloc < nMloc ? mloc : nMloc - 1;
    }
    const ushort* pb = Bpack + (size_t)bn * 32768 + (size_t)seg * 1024
                             + (size_t)lc * 8;

    f32x4 acc[2][8];
    #pragma unroll
    for (int mi = 0; mi < 2; ++mi)
        #pragma unroll
        for (int f = 0; f < 8; ++f) acc[mi][f] = (f32x4){0.f, 0.f, 0.f, 0.f};

    #pragma unroll
    for (int kk = 0; kk < 8; ++kk) {
        const int hi = kk >> 2, off = (kk & 3) * 32;
        s8v a0 = *(const s8v*)(&hIn[2 * mlc[0] + hi][off + koff]);
        s8v a1 = *(const s8v*)(&hIn[2 * mlc[1] + hi][off + koff]);
        #pragma unroll
        for (int f = 0; f < 8; ++f) {
            s8v bb = *(const s8v*)(pb + (size_t)kk * 4096 + f * 128);
            acc[0][f] = __builtin_amdgcn_mfma_f32_16x16x32_bf16(a0, bb, acc[0][f], 0, 0, 0);
            acc[1][f] = __builtin_amdgcn_mfma_f32_16x16x32_bf16(a1, bb, acc[1][f], 0, 0, 0);
        }
    }
    #pragma unroll
    for (int bh = 0; bh < 2; ++bh) {
        const int j = bn * 32 + bh * 16 + lc;
        const float4 wc = Wcol4[j];
        #pragma unroll
        for (int mi = 0; mi < 2; ++mi) {
            #pragma unroll
            for (int r = 0; r < 4; ++r) {
                const int mloc = wm2 * 32 + mi * 16 + seg * 4 + r;
                if (mloc < nMloc) {
                    const int node = startM + 64 * b + mloc;
                    const int ty = nt[node];
                    const float corr = (ty == 1) ? (na[node] - e1)
                                     : ((ty == 2) ? (na[node] - e2) : 0.0f);
                    const float4 px = PX4[(size_t)ty * 128 + j];
                    const float gi = acc[mi][bh * 4 + 0][r] + px.x + corr * wc.x;
                    const float gf = acc[mi][bh * 4 + 1][r] + px.y + corr * wc.y;
                    const float gg = acc[mi][bh * 4 + 2][r] + px.z + corr * wc.z;
                    const float go = acc[mi][bh * 4 + 3][r] + px.w + corr * wc.w;
                    const float c0 = cIn[mloc][j];
                    const float cn = sigf(gf) * c0 + sigf(gi) * tanh_fast(gg);
                    const float hn = sigf(go) * tanh_fast(cn);
                    hO[mloc][j] = f2bf(hn);
                    if (!(mloc & 1)) cO[mloc >> 1][j] = cn;
                }
            }
        }
    }
}

// M=32 GEMM, children from LDS. OUT: 0=global h/c, 1=LDS h/c, 2=root hs.
template<int OUT>
__device__ __forceinline__ void gemm32_lds(
    int b, int nT, int startT,
    const int* __restrict__ nt, const float* __restrict__ na,
    const ushort (*hIn)[136], const float (*cIn)[132],
    const ushort* __restrict__ Bpack, const float4* __restrict__ PX4,
    const float4* __restrict__ Wcol4, float e1, float e2,
    ushort* __restrict__ h_out, float* __restrict__ c_out,
    ushort (*hOL)[136], float (*cOL)[132], float* hs)
{
    const int tid  = threadIdx.x;
    const int lane = tid & 63;
    const int wave = tid >> 6;
    const int bn = wave >> 1, wn = wave & 1;
    const int lc = lane & 15, seg = lane >> 4;
    const int koff = seg * 8;
    int nTloc = nT - 32 * b; if (nTloc > 32) nTloc = 32;

    int mcl[2];
    #pragma unroll
    for (int mi = 0; mi < 2; ++mi) {
        int m = mi * 16 + lc;
        mcl[mi] = m < nTloc ? m : nTloc - 1;
    }
    const ushort* pb = Bpack + (size_t)bn * 32768 + (size_t)seg * 1024
                             + (size_t)(wn * 64 + lc) * 8;

    f32x4 acc[2][4];
    #pragma unroll
    for (int mi = 0; mi < 2; ++mi)
        #pragma unroll
        for (int f = 0; f < 4; ++f) acc[mi][f] = (f32x4){0.f, 0.f, 0.f, 0.f};

    #pragma unroll
    for (int kk = 0; kk < 8; ++kk) {
        const int hi = kk >> 2, off = (kk & 3) * 32;
        s8v a0 = *(const s8v*)(&hIn[2 * mcl[0] + hi][off + koff]);
        s8v a1 = *(const s8v*)(&hIn[2 * mcl[1] + hi][off + koff]);
        #pragma unroll
        for (int f = 0; f < 4; ++f) {
            s8v bb = *(const s8v*)(pb + (size_t)kk * 4096 + f * 128);
            acc[0][f] = __builtin_amdgcn_mfma_f32_16x16x32_bf16(a0, bb, acc[0][f], 0, 0, 0);
            acc[1][f] = __builtin_amdgcn_mfma_f32_16x16x32_bf16(a1, bb, acc[1][f], 0, 0, 0);
        }
    }

    const int j = bn * 32 + wn * 16 + lc;
    const float4 wc = Wcol4[j];
    #pragma unroll
    for (int mi = 0; mi < 2; ++mi) {
        #pragma unroll
        for (int r = 0; r < 4; ++r) {
            const int m = mi * 16 + seg * 4 + r;
            if (m < nTloc) {
                const int mPg = 32 * b + m;
                const int node = startT + mPg;
                const int ty = nt[node];
                const float corr = (ty == 1) ? (na[node] - e1)
                                 : ((ty == 2) ? (na[node] - e2) : 0.0f);
                const float4 px = PX4[(size_t)ty * 128 + j];
                const float gi = acc[mi][0][r] + px.x + corr * wc.x;
                const float gf = acc[mi][1][r] + px.y + corr * wc.y;
                const float gg = acc[mi][2][r] + px.z + corr * wc.z;
                const float go = acc[mi][3][r] + px.w + corr * wc.w;
                const float c0 = cIn[m][j];
                const float cn = sigf(gf) * c0 + sigf(gi) * tanh_fast(gg);
                const float hn = sigf(go) * tanh_fast(cn);
                if (OUT == 0) {
                    h_out[(size_t)mPg * 128 + j] = f2bf(hn);
                    if (!(mPg & 1)) c_out[(size_t)(mPg >> 1) * 128 + j] = cn;
                } else if (OUT == 1) {
                    hOL[m][j] = f2bf(hn);
                    if (!(m & 1)) cOL[m >> 1][j] = cn;
                } else {
                    hs[j] = hn;
                }
            }
        }
    }
}

// ---------------- trio: 3 levels per launch (deep 128 -> mid 64 -> top 32 per block) ----------------
template<bool LEAF>
__global__ __launch_bounds__(512) void trio(
    const int* __restrict__ nt, const float* __restrict__ na,
    const float* __restrict__ emb,
    const ushort* __restrict__ Bpack, const float4* __restrict__ PX4,
    const float4* __restrict__ Wcol4,
    const ushort* __restrict__ HLEAF, const float* __restrict__ CLEAF,
    const ushort* __restrict__ h_in, const float* __restrict__ c_in,
    ushort* __restrict__ h_out, float* __restrict__ c_out,
    int startD, int startM, int startT, int nD, int nM, int nT)
{
    __shared__ __align__(16) ushort hD[128][136];
    __shared__ float cD[64][132];
    __shared__ __align__(16) ushort hM[64][136];
    __shared__ float cM[32][132];

    const int tid = threadIdx.x;
    const int b = blockIdx.x;
    const float e1 = emb[255], e2 = emb[383];

    if (LEAF) {
        // 128 leaves per block: coalesced row copies from HLEAF/CLEAF
        const int mloc = tid >> 2;   // 0..127
        const int p4   = tid & 3;    // 32-elem chunk
        const int node = startD + 128 * b + mloc;
        const int ty = nt[node];
        if (ty != 1 && ty != 2) {
            #pragma unroll
            for (int q = 0; q < 4; ++q)
                *(s8v*)(&hD[mloc][p4 * 32 + q * 8]) =
                    *(const s8v*)(HLEAF + (size_t)ty * 128 + p4 * 32 + q * 8);
            if (!(mloc & 1)) {
                const float* cr = CLEAF + (size_t)ty * 128 + p4 * 32;
                #pragma unroll
                for (int q = 0; q < 32; ++q) cD[mloc >> 1][p4 * 32 + q] = cr[q];
            }
        } else {
            const float corr = na[node] - ((ty == 1) ? e1 : e2);
            #pragma unroll
            for (int q = 0; q < 32; ++q) {
                const int jj = p4 * 32 + q;
                const float4 px = PX4[(size_t)ty * 128 + jj];
                const float4 wc = Wcol4[jj];
                const float gi = px.x + corr * wc.x;
                const float gg = px.z + corr * wc.z;
                const float go = px.w + corr * wc.w;
                const float cn = sigf(gi) * tanh_fast(gg);
                const float hn = sigf(go) * tanh_fast(cn);
                hD[mloc][jj] = f2bf(hn);
                if (!(mloc & 1)) cD[mloc >> 1][jj] = cn;
            }
        }
    } else {
        gemm64_global(128 * b, nD, startD, nt, na, h_in, c_in,
                      Bpack, PX4, Wcol4, e1, e2, hD, cD);
        if (nD - 128 * b > 64)
            gemm64_global(128 * b + 64, nD, startD, nt, na, h_in, c_in,
                          Bpack, PX4, Wcol4, e1, e2, hD + 64, cD + 32);
    }
    __syncthreads();
    gemm64_lds(b, nM, startM, nt, na, hD, cD, Bpack, PX4, Wcol4, e1, e2, hM, cM);
    __syncthreads();
    gemm32_lds<0>(b, nT, startT, nt, na, hM, cM, Bpack, PX4, Wcol4, e1, e2,
                  h_out, c_out, nullptr, nullptr, nullptr);
}

// ---------------- final: levels 3..0 + MLP head, one block ----------------
__global__ __launch_bounds__(512) void final_k(
    const int* __restrict__ nt, const float* __restrict__ na,
    const float* __restrict__ emb,
    const ushort* __restrict__ Bpack, const float4* __restrict__ PX4,
    const float4* __restrict__ Wcol4,
    const ushort* __restrict__ h_in, const float* __restrict__ c_in,  // level 4
    const float* __restrict__ W1, const float* __restrict__ b1,
    const float* __restrict__ W2, const float* __restrict__ b2,
    const float* __restrict__ vmask, float* __restrict__ out)
{
    __shared__ __align__(16) ushort hD[128][136];
    __shared__ float cD[64][132];
    __shared__ __align__(16) ushort hM[64][136];
    __shared__ float cM[32][132];
    __shared__ __align__(16) ushort h1[4][136];
    __shared__ float c1[2][132];
    __shared__ float hs[128];
    __shared__ float as[128];

    const int tid = threadIdx.x;
    const float e1 = emb[255], e2 = emb[383];

    // S1: level 3 (8 nodes)
    gemm64_global(0, 8, 7, nt, na, h_in, c_in, Bpack, PX4, Wcol4, e1, e2, hD, cD);
    __syncthreads();
    // S2: level 2 (4 nodes)
    gemm64_lds(0, 4, 3, nt, na, hD, cD, Bpack, PX4, Wcol4, e1, e2, hM, cM);
    __syncthreads();
    // S3: level 1 (2 nodes) -> LDS
    gemm32_lds<1>(0, 2, 1, nt, na, hM, cM, Bpack, PX4, Wcol4, e1, e2,
                  nullptr, nullptr, h1, c1, nullptr);
    __syncthreads();
    // S4: root -> hs
    gemm32_lds<2>(0, 1, 0, nt, na, h1, c1, Bpack, PX4, Wcol4, e1, e2,
                  nullptr, nullptr, nullptr, nullptr, hs);
    __syncthreads();
    // head
    if (tid < 128) {
        float a1h = b1[tid];
        #pragma unroll 4
        for (int k = 0; k < 128; ++k) a1h = fmaf(hs[k], W1[tid * 128 + k], a1h);
        as[tid] = fmaxf(a1h, 0.0f);
    }
    __syncthreads();
    if (tid < 32) {
        float l = b2[tid];
        #pragma unroll 4
        for (int k = 0; k < 128; ++k) l = fmaf(as[k], W2[tid * 128 + k], l);
        l = (l + logf(vmask[tid])) * (1.0f / 3.0f);
        float mx = l;
        #pragma unroll
        for (int o = 16; o >= 1; o >>= 1) mx = fmaxf(mx, __shfl_xor(mx, o, 32));
        const float e = __expf(l - mx);
        float s = e;
        #pragma unroll
        for (int o = 16; o >= 1; o >>= 1) s += __shfl_xor(s, o, 32);
        out[tid] = e / s;
    }
}

extern "C" void kernel_launch(void* const* d_in, const int* in_sizes, int n_in,
                              void* d_out, int out_size, void* d_ws, size_t ws_size,
                              hipStream_t stream)
{
    const int*   node_types = (const int*)  d_in[0];
    const float* node_args  = (const float*)d_in[1];
    const float* vmask      = (const float*)d_in[2];
    const float* emb        = (const float*)d_in[3];
    const float* Wih        = (const float*)d_in[4];
    const float* Whh        = (const float*)d_in[5];
    const float* bih        = (const float*)d_in[6];
    const float* bhh        = (const float*)d_in[7];
    const float* W1         = (const float*)d_in[8];
    const float* b1         = (const float*)d_in[9];
    const float* W2         = (const float*)d_in[10];
    const float* b2         = (const float*)d_in[11];

    char* w = (char*)d_ws;
    ushort* Bpack = (ushort*)(w);                 // 16384*8*2  =   262,144
    float4* PX4   = (float4*)(w + 262144);        // 16384*16   =   262,144
    float4* Wcol4 = (float4*)(w + 524288);        // 128*16     =     2,048
    ushort* HLEAF = (ushort*)(w + 526336);        // 16384*2    =    32,768
    float*  CLEAF = (float*) (w + 559104);        // 16384*4    =    65,536
    ushort* hA    = (ushort*)(w + 624640);        // 8192*128*2 = 2,097,152
    float*  cA    = (float*) (w + 2721792);       // 4096*128*4 = 2,097,152
    ushort* hB    = (ushort*)(w + 4818944);       // 1024*128*2 =   262,144
    float*  cB    = (float*) (w + 5081088);       // 512*128*4  =   262,144

    float* out = (float*)d_out;

    prepass<<<128, 256, 0, stream>>>(emb, Wih, Whh, bih, bhh,
                                     Bpack, PX4, Wcol4, HLEAF, CLEAF);

    // trio (15,14,13): leaves copied, out -> hA/cA (level-13)
    trio<true><<<256, 512, 0, stream>>>(node_types, node_args, emb,
        Bpack, PX4, Wcol4, HLEAF, CLEAF, hB, cB, hA, cA,
        32767, 16383, 8191, 32768, 16384, 8192);
    // trio (12,11,10): hA -> hB (level-10)
    trio<false><<<32, 512, 0, stream>>>(node_types, node_args, emb,
        Bpack, PX4, Wcol4, HLEAF, CLEAF, hA, cA, hB, cB,
        4095, 2047, 1023, 4096, 2048, 1024);
    // trio (9,8,7): hB -> hA (level-7, 128 rows)
    trio<false><<<4, 512, 0, stream>>>(node_types, node_args, emb,
        Bpack, PX4, Wcol4, HLEAF, CLEAF, hB, cB, hA, cA,
        511, 255, 127, 512, 256, 128);
    // trio (6,5,4): hA -> hB (level-4, 16 rows)
    trio<false><<<1, 512, 0, stream>>>(node_types, node_args, emb,
        Bpack, PX4, Wcol4, HLEAF, CLEAF, hA, cA, hB, cB,
        63, 31, 15, 64, 32, 16);
    // final (3,2,1,0) + head: reads hB (level-4)
    final_k<<<1, 512, 0, stream>>>(node_types, node_args, emb,
        Bpack, PX4, Wcol4, hB, cB, W1, b1, W2, b2, vmask, out);
}

// Round 18
// 168.429 us; speedup vs baseline: 1.7439x; 1.7439x over previous
//
#include <hip/hip_runtime.h>
#include <hip/hip_bf16.h>

typedef __attribute__((ext_vector_type(8))) short s8v;   // 8 x bf16
typedef __attribute__((ext_vector_type(4))) float f32x4; // MFMA acc

__device__ __forceinline__ float sigf(float x) { return 1.0f / (1.0f + __expf(-x)); }
__device__ __forceinline__ float tanh_fast(float x) { return 1.0f - 2.0f / (1.0f + __expf(2.0f * x)); }
__device__ __forceinline__ ushort f2bf(float f) {
    union { __hip_bfloat16 b; ushort u; } v; v.b = __float2bfloat16(f); return v.u;
}

// ---------------- prepass (R16-proven) ----------------
__global__ __launch_bounds__(256) void prepass(
    const float* __restrict__ emb,
    const float* __restrict__ Wih, const float* __restrict__ Whh,
    const float* __restrict__ bih, const float* __restrict__ bhh,
    ushort* __restrict__ Bpack, float4* __restrict__ PX4, float4* __restrict__ Wcol4,
    ushort* __restrict__ HLEAF, float* __restrict__ CLEAF)
{
    const int bx = blockIdx.x;
    const int tid = threadIdx.x;
    if (bx < 64) {
        const int gid = bx * 256 + tid;     // (ty, j)
        const int ty = gid >> 7;
        const int j  = gid & 127;
        const float* e = emb + (size_t)ty * 128;
        float d[4];
        #pragma unroll
        for (int g = 0; g < 4; ++g) {
            const int row = g * 256 + j;
            const float* wr = Wih + (size_t)row * 128;
            float acc = bih[row] + bhh[row];
            #pragma unroll 8
            for (int k = 0; k < 128; k += 4) {
                float4 ev = *(const float4*)(e + k);
                float4 wv = *(const float4*)(wr + k);
                acc = fmaf(ev.x, wv.x, acc); acc = fmaf(ev.y, wv.y, acc);
                acc = fmaf(ev.z, wv.z, acc); acc = fmaf(ev.w, wv.w, acc);
            }
            d[g] = acc;
        }
        PX4[gid] = make_float4(d[0], d[1], d[2], d[3]);
        const float cn = sigf(d[0]) * tanh_fast(d[2]);
        CLEAF[gid] = cn;
        HLEAF[gid] = f2bf(sigf(d[3]) * tanh_fast(cn));
        if (ty == 0)
            Wcol4[j] = make_float4(Wih[(size_t)j * 128 + 127],
                                   Wih[(size_t)(256 + j) * 128 + 127],
                                   Wih[(size_t)(512 + j) * 128 + 127],
                                   Wih[(size_t)(768 + j) * 128 + 127]);
    } else {
        const int gid = (bx - 64) * 256 + tid;   // Bpack (Whh only, K=256)
        const int nl  = gid & 127;
        const int seg = (gid >> 7) & 3;
        const int rest = gid >> 9;
        const int kk = rest & 7;
        const int bn = rest >> 3;
        const int g  = (nl >> 4) & 3;
        const int j  = bn * 32 + ((nl >> 6) << 4) + (nl & 15);
        const int row = g * 256 + j;
        const int k = kk * 32 + seg * 8;
        const float* src = Whh + (size_t)row * 256 + k;
        float4 w0 = *(const float4*)(src);
        float4 w1 = *(const float4*)(src + 4);
        ushort o[8] = { f2bf(w0.x), f2bf(w0.y), f2bf(w0.z), f2bf(w0.w),
                        f2bf(w1.x), f2bf(w1.y), f2bf(w1.z), f2bf(w1.w) };
        *(s8v*)(Bpack + (size_t)gid * 8) = *(const s8v*)o;
    }
}

// ---------------- helpers (pair-proven pressure: one live acc set each) ----------------
// M=64 rows of a level, children h/c from GLOBAL -> LDS hO/cO (local rows 0..63).
__device__ __forceinline__ void gemm64_g(
    int rowbase, int nRows, int startL,
    const int* __restrict__ nt, const float* __restrict__ na,
    const ushort* __restrict__ h_in, const float* __restrict__ c_in,
    const ushort* __restrict__ Bpack, const float4* __restrict__ PX4,
    const float4* __restrict__ Wcol4, float e1, float e2,
    ushort (*hO)[136], float (*cO)[132])
{
    const int tid  = threadIdx.x;
    const int lane = tid & 63;
    const int wave = tid >> 6;
    const int wm2 = wave >> 2;
    const int bn  = wave & 3;
    const int lc = lane & 15, seg = lane >> 4;
    const int koff = seg * 8;

    const ushort* ph[2][2];
    #pragma unroll
    for (int mi = 0; mi < 2; ++mi) {
        int mloc = wm2 * 32 + mi * 16 + lc;
        int dg = rowbase + mloc;
        int dgc = dg < nRows ? dg : nRows - 1;
        ph[mi][0] = h_in + (size_t)(2 * dgc) * 128 + koff;
        ph[mi][1] = h_in + (size_t)(2 * dgc + 1) * 128 + koff;
    }
    const ushort* pb = Bpack + (size_t)bn * 32768 + (size_t)seg * 1024
                             + (size_t)lc * 8;

    f32x4 acc[2][8];
    #pragma unroll
    for (int mi = 0; mi < 2; ++mi)
        #pragma unroll
        for (int f = 0; f < 8; ++f) acc[mi][f] = (f32x4){0.f, 0.f, 0.f, 0.f};

    #pragma unroll
    for (int kk = 0; kk < 8; ++kk) {
        const int hi = kk >> 2, off = (kk & 3) * 32;
        s8v a0 = *(const s8v*)(ph[0][hi] + off);
        s8v a1 = *(const s8v*)(ph[1][hi] + off);
        #pragma unroll
        for (int f = 0; f < 8; ++f) {
            s8v bb = *(const s8v*)(pb + (size_t)kk * 4096 + f * 128);
            acc[0][f] = __builtin_amdgcn_mfma_f32_16x16x32_bf16(a0, bb, acc[0][f], 0, 0, 0);
            acc[1][f] = __builtin_amdgcn_mfma_f32_16x16x32_bf16(a1, bb, acc[1][f], 0, 0, 0);
        }
    }
    #pragma unroll
    for (int bh = 0; bh < 2; ++bh) {
        const int j = bn * 32 + bh * 16 + lc;
        const float4 wc = Wcol4[j];
        #pragma unroll
        for (int mi = 0; mi < 2; ++mi) {
            #pragma unroll
            for (int r = 0; r < 4; ++r) {
                const int mloc = wm2 * 32 + mi * 16 + seg * 4 + r;
                const int dg = rowbase + mloc;
                if (dg < nRows) {
                    const int node = startL + dg;
                    const int ty = nt[node];
                    const float corr = (ty == 1) ? (na[node] - e1)
                                     : ((ty == 2) ? (na[node] - e2) : 0.0f);
                    const float4 px = PX4[(size_t)ty * 128 + j];
                    const float gi = acc[mi][bh * 4 + 0][r] + px.x + corr * wc.x;
                    const float gf = acc[mi][bh * 4 + 1][r] + px.y + corr * wc.y;
                    const float gg = acc[mi][bh * 4 + 2][r] + px.z + corr * wc.z;
                    const float go = acc[mi][bh * 4 + 3][r] + px.w + corr * wc.w;
                    const float c0 = c_in[(size_t)dg * 128 + j];
                    const float cn = sigf(gf) * c0 + sigf(gi) * tanh_fast(gg);
                    const float hn = sigf(go) * tanh_fast(cn);
                    hO[mloc][j] = f2bf(hn);
                    if (!(mloc & 1)) cO[mloc >> 1][j] = cn;
                }
            }
        }
    }
}

// M<=32 rows, children h/c from LDS. OUT: 0=global, 1=LDS, 2=root hs.
template<int OUT>
__device__ __forceinline__ void gemm32_l(
    int gbase, int nloc, int startL,
    const int* __restrict__ nt, const float* __restrict__ na,
    const ushort (*hIn)[136], const float (*cIn)[132],
    const ushort* __restrict__ Bpack, const float4* __restrict__ PX4,
    const float4* __restrict__ Wcol4, float e1, float e2,
    ushort* __restrict__ h_out, float* __restrict__ c_out,
    ushort (*hOL)[136], float (*cOL)[132], float* hs)
{
    const int tid  = threadIdx.x;
    const int lane = tid & 63;
    const int wave = tid >> 6;
    const int bn = wave >> 1, wn = wave & 1;
    const int lc = lane & 15, seg = lane >> 4;
    const int koff = seg * 8;

    int mcl[2];
    #pragma unroll
    for (int mi = 0; mi < 2; ++mi) {
        int m = mi * 16 + lc;
        mcl[mi] = m < nloc ? m : nloc - 1;
    }
    const ushort* pb = Bpack + (size_t)bn * 32768 + (size_t)seg * 1024
                             + (size_t)(wn * 64 + lc) * 8;

    f32x4 acc[2][4];
    #pragma unroll
    for (int mi = 0; mi < 2; ++mi)
        #pragma unroll
        for (int f = 0; f < 4; ++f) acc[mi][f] = (f32x4){0.f, 0.f, 0.f, 0.f};

    #pragma unroll
    for (int kk = 0; kk < 8; ++kk) {
        const int hi = kk >> 2, off = (kk & 3) * 32;
        s8v a0 = *(const s8v*)(&hIn[2 * mcl[0] + hi][off + koff]);
        s8v a1 = *(const s8v*)(&hIn[2 * mcl[1] + hi][off + koff]);
        #pragma unroll
        for (int f = 0; f < 4; ++f) {
            s8v bb = *(const s8v*)(pb + (size_t)kk * 4096 + f * 128);
            acc[0][f] = __builtin_amdgcn_mfma_f32_16x16x32_bf16(a0, bb, acc[0][f], 0, 0, 0);
            acc[1][f] = __builtin_amdgcn_mfma_f32_16x16x32_bf16(a1, bb, acc[1][f], 0, 0, 0);
        }
    }

    const int j = bn * 32 + wn * 16 + lc;
    const float4 wc = Wcol4[j];
    #pragma unroll
    for (int mi = 0; mi < 2; ++mi) {
        #pragma unroll
        for (int r = 0; r < 4; ++r) {
            const int m = mi * 16 + seg * 4 + r;
            if (m < nloc) {
                const int mPg = gbase + m;
                const int node = startL + mPg;
                const int ty = nt[node];
                const float corr = (ty == 1) ? (na[node] - e1)
                                 : ((ty == 2) ? (na[node] - e2) : 0.0f);
                const float4 px = PX4[(size_t)ty * 128 + j];
                const float gi = acc[mi][0][r] + px.x + corr * wc.x;
                const float gf = acc[mi][1][r] + px.y + corr * wc.y;
                const float gg = acc[mi][2][r] + px.z + corr * wc.z;
                const float go = acc[mi][3][r] + px.w + corr * wc.w;
                const float c0 = cIn[m][j];
                const float cn = sigf(gf) * c0 + sigf(gi) * tanh_fast(gg);
                const float hn = sigf(go) * tanh_fast(cn);
                if (OUT == 0) {
                    h_out[(size_t)mPg * 128 + j] = f2bf(hn);
                    if (!(mPg & 1)) c_out[(size_t)(mPg >> 1) * 128 + j] = cn;
                } else if (OUT == 1) {
                    hOL[m][j] = f2bf(hn);
                    if (!(m & 1)) cOL[m >> 1][j] = cn;
                } else {
                    hs[j] = hn;
                }
            }
        }
    }
}

// ---------------- trio: 3 levels/launch (64 deep -> 32 mid -> 16 top per block) ----------------
template<bool LEAF>
__global__ __launch_bounds__(512) void trio(
    const int* __restrict__ nt, const float* __restrict__ na,
    const float* __restrict__ emb,
    const ushort* __restrict__ Bpack, const float4* __restrict__ PX4,
    const float4* __restrict__ Wcol4,
    const ushort* __restrict__ HLEAF, const float* __restrict__ CLEAF,
    const ushort* __restrict__ h_in, const float* __restrict__ c_in,
    ushort* __restrict__ h_out, float* __restrict__ c_out,
    int startD, int startM, int startT, int nD)
{
    __shared__ __align__(16) ushort hD[64][136];
    __shared__ float cD[32][132];
    __shared__ __align__(16) ushort hM[32][136];
    __shared__ float cM[16][132];

    const int tid = threadIdx.x;
    const int b = blockIdx.x;
    const float e1 = emb[255], e2 = emb[383];

    if (LEAF) {
        // 64 leaves per block: coalesced row copies (R16-proven pattern)
        const int mloc = tid >> 3;      // 0..63
        const int p8   = tid & 7;       // 16-elem chunk
        const int node = startD + 64 * b + mloc;
        const int ty = nt[node];
        if (ty != 1 && ty != 2) {
            *(s8v*)(&hD[mloc][p8 * 16])     = *(const s8v*)(HLEAF + (size_t)ty * 128 + p8 * 16);
            *(s8v*)(&hD[mloc][p8 * 16 + 8]) = *(const s8v*)(HLEAF + (size_t)ty * 128 + p8 * 16 + 8);
            if (!(mloc & 1)) {
                const float* cr = CLEAF + (size_t)ty * 128 + p8 * 16;
                #pragma unroll
                for (int q = 0; q < 16; ++q) cD[mloc >> 1][p8 * 16 + q] = cr[q];
            }
        } else {
            const float corr = na[node] - ((ty == 1) ? e1 : e2);
            #pragma unroll
            for (int q = 0; q < 16; ++q) {
                const int jj = p8 * 16 + q;
                const float4 px = PX4[(size_t)ty * 128 + jj];
                const float4 wc = Wcol4[jj];
                const float gi = px.x + corr * wc.x;
                const float gg = px.z + corr * wc.z;
                const float go = px.w + corr * wc.w;
                const float cn = sigf(gi) * tanh_fast(gg);
                const float hn = sigf(go) * tanh_fast(cn);
                hD[mloc][jj] = f2bf(hn);
                if (!(mloc & 1)) cD[mloc >> 1][jj] = cn;
            }
        }
    } else {
        gemm64_g(64 * b, nD, startD, nt, na, h_in, c_in,
                 Bpack, PX4, Wcol4, e1, e2, hD, cD);
    }
    __syncthreads();
    gemm32_l<1>(32 * b, 32, startM, nt, na, hD, cD, Bpack, PX4, Wcol4, e1, e2,
                nullptr, nullptr, hM, cM, nullptr);
    __syncthreads();
    gemm32_l<0>(16 * b, 16, startT, nt, na, hM, cM, Bpack, PX4, Wcol4, e1, e2,
                h_out, c_out, nullptr, nullptr, nullptr);
}

// ---------------- final: levels 3..0 + MLP head, one block ----------------
__global__ __launch_bounds__(512) void final_k(
    const int* __restrict__ nt, const float* __restrict__ na,
    const float* __restrict__ emb,
    const ushort* __restrict__ Bpack, const float4* __restrict__ PX4,
    const float4* __restrict__ Wcol4,
    const ushort* __restrict__ h_in, const float* __restrict__ c_in,  // level 4 (16 rows)
    const float* __restrict__ W1, const float* __restrict__ b1,
    const float* __restrict__ W2, const float* __restrict__ b2,
    const float* __restrict__ vmask, float* __restrict__ out)
{
    __shared__ __align__(16) ushort hD[64][136];
    __shared__ float cD[32][132];
    __shared__ __align__(16) ushort hM[32][136];
    __shared__ float cM[16][132];
    __shared__ float hs[128];
    __shared__ float as[128];

    const int tid = threadIdx.x;
    const float e1 = emb[255], e2 = emb[383];

    // S1: level 3 (8 nodes) from global level-4
    gemm64_g(0, 8, 7, nt, na, h_in, c_in, Bpack, PX4, Wcol4, e1, e2, hD, cD);
    __syncthreads();
    // S2: level 2 (4 nodes) -> hM/cM
    gemm32_l<1>(0, 4, 3, nt, na, hD, cD, Bpack, PX4, Wcol4, e1, e2,
                nullptr, nullptr, hM, cM, nullptr);
    __syncthreads();
    // S3: level 1 (2 nodes) -> hD/cD (reuse)
    gemm32_l<1>(0, 2, 1, nt, na, hM, cM, Bpack, PX4, Wcol4, e1, e2,
                nullptr, nullptr, hD, cD, nullptr);
    __syncthreads();
    // S4: root -> hs
    gemm32_l<2>(0, 1, 0, nt, na, hD, cD, Bpack, PX4, Wcol4, e1, e2,
                nullptr, nullptr, nullptr, nullptr, hs);
    __syncthreads();
    // head
    if (tid < 128) {
        float a1h = b1[tid];
        #pragma unroll 4
        for (int k = 0; k < 128; ++k) a1h = fmaf(hs[k], W1[tid * 128 + k], a1h);
        as[tid] = fmaxf(a1h, 0.0f);
    }
    __syncthreads();
    if (tid < 32) {
        float l = b2[tid];
        #pragma unroll 4
        for (int k = 0; k < 128; ++k) l = fmaf(as[k], W2[tid * 128 + k], l);
        l = (l + logf(vmask[tid])) * (1.0f / 3.0f);
        float mx = l;
        #pragma unroll
        for (int o = 16; o >= 1; o >>= 1) mx = fmaxf(mx, __shfl_xor(mx, o, 32));
        const float e = __expf(l - mx);
        float s = e;
        #pragma unroll
        for (int o = 16; o >= 1; o >>= 1) s += __shfl_xor(s, o, 32);
        out[tid] = e / s;
    }
}

extern "C" void kernel_launch(void* const* d_in, const int* in_sizes, int n_in,
                              void* d_out, int out_size, void* d_ws, size_t ws_size,
                              hipStream_t stream)
{
    const int*   node_types = (const int*)  d_in[0];
    const float* node_args  = (const float*)d_in[1];
    const float* vmask      = (const float*)d_in[2];
    const float* emb        = (const float*)d_in[3];
    const float* Wih        = (const float*)d_in[4];
    const float* Whh        = (const float*)d_in[5];
    const float* bih        = (const float*)d_in[6];
    const float* bhh        = (const float*)d_in[7];
    const float* W1         = (const float*)d_in[8];
    const float* b1         = (const float*)d_in[9];
    const float* W2         = (const float*)d_in[10];
    const float* b2         = (const float*)d_in[11];

    char* w = (char*)d_ws;
    ushort* Bpack = (ushort*)(w);                 // 16384*8*2  =   262,144
    float4* PX4   = (float4*)(w + 262144);        // 16384*16   =   262,144
    float4* Wcol4 = (float4*)(w + 524288);        // 128*16     =     2,048
    ushort* HLEAF = (ushort*)(w + 526336);        // 16384*2    =    32,768
    float*  CLEAF = (float*) (w + 559104);        // 16384*4    =    65,536
    ushort* hA    = (ushort*)(w + 624640);        // 8192*128*2 = 2,097,152
    float*  cA    = (float*) (w + 2721792);       // 4096*128*4 = 2,097,152
    ushort* hB    = (ushort*)(w + 4818944);       // 1024*128*2 =   262,144
    float*  cB    = (float*) (w + 5081088);       // 512*128*4  =   262,144

    float* out = (float*)d_out;

    prepass<<<128, 256, 0, stream>>>(emb, Wih, Whh, bih, bhh,
                                     Bpack, PX4, Wcol4, HLEAF, CLEAF);

    // trio (15,14,13): leaves copied -> level-13 in hA/cA
    trio<true><<<512, 512, 0, stream>>>(node_types, node_args, emb,
        Bpack, PX4, Wcol4, HLEAF, CLEAF, hB, cB, hA, cA,
        32767, 16383, 8191, 32768);
    // trio (12,11,10): hA -> hB (level-10)
    trio<false><<<64, 512, 0, stream>>>(node_types, node_args, emb,
        Bpack, PX4, Wcol4, HLEAF, CLEAF, hA, cA, hB, cB,
        4095, 2047, 1023, 4096);
    // trio (9,8,7): hB -> hA (level-7)
    trio<false><<<8, 512, 0, stream>>>(node_types, node_args, emb,
        Bpack, PX4, Wcol4, HLEAF, CLEAF, hB, cB, hA, cA,
        511, 255, 127, 512);
    // trio (6,5,4): hA -> hB (level-4)
    trio<false><<<1, 512, 0, stream>>>(node_types, node_args, emb,
        Bpack, PX4, Wcol4, HLEAF, CLEAF, hA, cA, hB, cB,
        63, 31, 15, 64);
    // final (3,2,1,0) + head
    final_k<<<1, 512, 0, stream>>>(node_types, node_args, emb,
        Bpack, PX4, Wcol4, hB, cB, W1, b1, W2, b2, vmask, out);
}

// Round 19
// 141.244 us; speedup vs baseline: 2.0795x; 1.1925x over previous
//
#include <hip/hip_runtime.h>
#include <hip/hip_bf16.h>

typedef __attribute__((ext_vector_type(8))) short s8v;   // 8 x bf16
typedef __attribute__((ext_vector_type(4))) float f32x4; // MFMA acc

__device__ __forceinline__ float sigf(float x) { return 1.0f / (1.0f + __expf(-x)); }
__device__ __forceinline__ float tanh_fast(float x) { return 1.0f - 2.0f / (1.0f + __expf(2.0f * x)); }
__device__ __forceinline__ ushort f2bf(float f) {
    union { __hip_bfloat16 b; ushort u; } v; v.b = __float2bfloat16(f); return v.u;
}

// ---------------- prepass (R16-proven) ----------------
__global__ __launch_bounds__(256) void prepass(
    const float* __restrict__ emb,
    const float* __restrict__ Wih, const float* __restrict__ Whh,
    const float* __restrict__ bih, const float* __restrict__ bhh,
    ushort* __restrict__ Bpack, float4* __restrict__ PX4, float4* __restrict__ Wcol4,
    ushort* __restrict__ HLEAF, float* __restrict__ CLEAF)
{
    const int bx = blockIdx.x;
    const int tid = threadIdx.x;
    if (bx < 64) {
        const int gid = bx * 256 + tid;     // (ty, j)
        const int ty = gid >> 7;
        const int j  = gid & 127;
        const float* e = emb + (size_t)ty * 128;
        float d[4];
        #pragma unroll
        for (int g = 0; g < 4; ++g) {
            const int row = g * 256 + j;
            const float* wr = Wih + (size_t)row * 128;
            float acc = bih[row] + bhh[row];
            #pragma unroll 8
            for (int k = 0; k < 128; k += 4) {
                float4 ev = *(const float4*)(e + k);
                float4 wv = *(const float4*)(wr + k);
                acc = fmaf(ev.x, wv.x, acc); acc = fmaf(ev.y, wv.y, acc);
                acc = fmaf(ev.z, wv.z, acc); acc = fmaf(ev.w, wv.w, acc);
            }
            d[g] = acc;
        }
        PX4[gid] = make_float4(d[0], d[1], d[2], d[3]);
        const float cn = sigf(d[0]) * tanh_fast(d[2]);
        CLEAF[gid] = cn;
        HLEAF[gid] = f2bf(sigf(d[3]) * tanh_fast(cn));
        if (ty == 0)
            Wcol4[j] = make_float4(Wih[(size_t)j * 128 + 127],
                                   Wih[(size_t)(256 + j) * 128 + 127],
                                   Wih[(size_t)(512 + j) * 128 + 127],
                                   Wih[(size_t)(768 + j) * 128 + 127]);
    } else {
        const int gid = (bx - 64) * 256 + tid;   // Bpack (Whh only, K=256)
        const int nl  = gid & 127;
        const int seg = (gid >> 7) & 3;
        const int rest = gid >> 9;
        const int kk = rest & 7;
        const int bn = rest >> 3;
        const int g  = (nl >> 4) & 3;
        const int j  = bn * 32 + ((nl >> 6) << 4) + (nl & 15);
        const int row = g * 256 + j;
        const int k = kk * 32 + seg * 8;
        const float* src = Whh + (size_t)row * 256 + k;
        float4 w0 = *(const float4*)(src);
        float4 w1 = *(const float4*)(src + 4);
        ushort o[8] = { f2bf(w0.x), f2bf(w0.y), f2bf(w0.z), f2bf(w0.w),
                        f2bf(w1.x), f2bf(w1.y), f2bf(w1.z), f2bf(w1.w) };
        *(s8v*)(Bpack + (size_t)gid * 8) = *(const s8v*)o;
    }
}

// ---------------- helpers (R18-proven; one live acc set, barrier-separated) ----------------
// 64 rows of a level, children h/c from GLOBAL -> LDS hO/cO.
__device__ __forceinline__ void gemm64_g(
    int rowbase, int nRows, int startL,
    const int* __restrict__ nt, const float* __restrict__ na,
    const ushort* __restrict__ h_in, const float* __restrict__ c_in,
    const ushort* __restrict__ Bpack, const float4* __restrict__ PX4,
    const float4* __restrict__ Wcol4, float e1, float e2,
    ushort (*hO)[136], float (*cO)[132])
{
    const int tid  = threadIdx.x;
    const int lane = tid & 63;
    const int wave = tid >> 6;
    const int wm2 = wave >> 2;
    const int bn  = wave & 3;
    const int lc = lane & 15, seg = lane >> 4;
    const int koff = seg * 8;

    const ushort* ph[2][2];
    #pragma unroll
    for (int mi = 0; mi < 2; ++mi) {
        int mloc = wm2 * 32 + mi * 16 + lc;
        int dg = rowbase + mloc;
        int dgc = dg < nRows ? dg : nRows - 1;
        ph[mi][0] = h_in + (size_t)(2 * dgc) * 128 + koff;
        ph[mi][1] = h_in + (size_t)(2 * dgc + 1) * 128 + koff;
    }
    const ushort* pb = Bpack + (size_t)bn * 32768 + (size_t)seg * 1024
                             + (size_t)lc * 8;

    f32x4 acc[2][8];
    #pragma unroll
    for (int mi = 0; mi < 2; ++mi)
        #pragma unroll
        for (int f = 0; f < 8; ++f) acc[mi][f] = (f32x4){0.f, 0.f, 0.f, 0.f};

    #pragma unroll
    for (int kk = 0; kk < 8; ++kk) {
        const int hi = kk >> 2, off = (kk & 3) * 32;
        s8v a0 = *(const s8v*)(ph[0][hi] + off);
        s8v a1 = *(const s8v*)(ph[1][hi] + off);
        #pragma unroll
        for (int f = 0; f < 8; ++f) {
            s8v bb = *(const s8v*)(pb + (size_t)kk * 4096 + f * 128);
            acc[0][f] = __builtin_amdgcn_mfma_f32_16x16x32_bf16(a0, bb, acc[0][f], 0, 0, 0);
            acc[1][f] = __builtin_amdgcn_mfma_f32_16x16x32_bf16(a1, bb, acc[1][f], 0, 0, 0);
        }
    }
    #pragma unroll
    for (int bh = 0; bh < 2; ++bh) {
        const int j = bn * 32 + bh * 16 + lc;
        const float4 wc = Wcol4[j];
        #pragma unroll
        for (int mi = 0; mi < 2; ++mi) {
            #pragma unroll
            for (int r = 0; r < 4; ++r) {
                const int mloc = wm2 * 32 + mi * 16 + seg * 4 + r;
                const int dg = rowbase + mloc;
                if (dg < nRows) {
                    const int node = startL + dg;
                    const int ty = nt[node];
                    const float corr = (ty == 1) ? (na[node] - e1)
                                     : ((ty == 2) ? (na[node] - e2) : 0.0f);
                    const float4 px = PX4[(size_t)ty * 128 + j];
                    const float gi = acc[mi][bh * 4 + 0][r] + px.x + corr * wc.x;
                    const float gf = acc[mi][bh * 4 + 1][r] + px.y + corr * wc.y;
                    const float gg = acc[mi][bh * 4 + 2][r] + px.z + corr * wc.z;
                    const float go = acc[mi][bh * 4 + 3][r] + px.w + corr * wc.w;
                    const float c0 = c_in[(size_t)dg * 128 + j];
                    const float cn = sigf(gf) * c0 + sigf(gi) * tanh_fast(gg);
                    const float hn = sigf(go) * tanh_fast(cn);
                    hO[mloc][j] = f2bf(hn);
                    if (!(mloc & 1)) cO[mloc >> 1][j] = cn;
                }
            }
        }
    }
}

// M<=32 rows, children h/c from LDS. OUT: 0=global, 1=LDS, 2=root hs.
template<int OUT>
__device__ __forceinline__ void gemm32_l(
    int gbase, int nloc, int startL,
    const int* __restrict__ nt, const float* __restrict__ na,
    const ushort (*hIn)[136], const float (*cIn)[132],
    const ushort* __restrict__ Bpack, const float4* __restrict__ PX4,
    const float4* __restrict__ Wcol4, float e1, float e2,
    ushort* __restrict__ h_out, float* __restrict__ c_out,
    ushort (*hOL)[136], float (*cOL)[132], float* hs)
{
    const int tid  = threadIdx.x;
    const int lane = tid & 63;
    const int wave = tid >> 6;
    const int bn = wave >> 1, wn = wave & 1;
    const int lc = lane & 15, seg = lane >> 4;
    const int koff = seg * 8;

    int mcl[2];
    #pragma unroll
    for (int mi = 0; mi < 2; ++mi) {
        int m = mi * 16 + lc;
        mcl[mi] = m < nloc ? m : nloc - 1;
    }
    const ushort* pb = Bpack + (size_t)bn * 32768 + (size_t)seg * 1024
                             + (size_t)(wn * 64 + lc) * 8;

    f32x4 acc[2][4];
    #pragma unroll
    for (int mi = 0; mi < 2; ++mi)
        #pragma unroll
        for (int f = 0; f < 4; ++f) acc[mi][f] = (f32x4){0.f, 0.f, 0.f, 0.f};

    #pragma unroll
    for (int kk = 0; kk < 8; ++kk) {
        const int hi = kk >> 2, off = (kk & 3) * 32;
        s8v a0 = *(const s8v*)(&hIn[2 * mcl[0] + hi][off + koff]);
        s8v a1 = *(const s8v*)(&hIn[2 * mcl[1] + hi][off + koff]);
        #pragma unroll
        for (int f = 0; f < 4; ++f) {
            s8v bb = *(const s8v*)(pb + (size_t)kk * 4096 + f * 128);
            acc[0][f] = __builtin_amdgcn_mfma_f32_16x16x32_bf16(a0, bb, acc[0][f], 0, 0, 0);
            acc[1][f] = __builtin_amdgcn_mfma_f32_16x16x32_bf16(a1, bb, acc[1][f], 0, 0, 0);
        }
    }

    const int j = bn * 32 + wn * 16 + lc;
    const float4 wc = Wcol4[j];
    #pragma unroll
    for (int mi = 0; mi < 2; ++mi) {
        #pragma unroll
        for (int r = 0; r < 4; ++r) {
            const int m = mi * 16 + seg * 4 + r;
            if (m < nloc) {
                const int mPg = gbase + m;
                const int node = startL + mPg;
                const int ty = nt[node];
                const float corr = (ty == 1) ? (na[node] - e1)
                                 : ((ty == 2) ? (na[node] - e2) : 0.0f);
                const float4 px = PX4[(size_t)ty * 128 + j];
                const float gi = acc[mi][0][r] + px.x + corr * wc.x;
                const float gf = acc[mi][1][r] + px.y + corr * wc.y;
                const float gg = acc[mi][2][r] + px.z + corr * wc.z;
                const float go = acc[mi][3][r] + px.w + corr * wc.w;
                const float c0 = cIn[m][j];
                const float cn = sigf(gf) * c0 + sigf(gi) * tanh_fast(gg);
                const float hn = sigf(go) * tanh_fast(cn);
                if (OUT == 0) {
                    h_out[(size_t)mPg * 128 + j] = f2bf(hn);
                    if (!(mPg & 1)) c_out[(size_t)(mPg >> 1) * 128 + j] = cn;
                } else if (OUT == 1) {
                    hOL[m][j] = f2bf(hn);
                    if (!(m & 1)) cOL[m >> 1][j] = cn;
                } else {
                    hs[j] = hn;
                }
            }
        }
    }
}

// ---------------- mega1: levels 15..11 per block (leafcopy + 4 GEMM stages) ----------------
__global__ __launch_bounds__(512) void mega1(
    const int* __restrict__ nt, const float* __restrict__ na,
    const float* __restrict__ emb,
    const ushort* __restrict__ Bpack, const float4* __restrict__ PX4,
    const float4* __restrict__ Wcol4,
    const ushort* __restrict__ HLEAF, const float* __restrict__ CLEAF,
    ushort* __restrict__ h_out, float* __restrict__ c_out)   // level-11
{
    __shared__ __align__(16) ushort hD[64][136];
    __shared__ float cD[32][132];
    __shared__ __align__(16) ushort hM[32][136];
    __shared__ float cM[16][132];

    const int tid = threadIdx.x;
    const int b = blockIdx.x;
    const float e1 = emb[255], e2 = emb[383];

    // stage 0: 64 leaves (level 15) via HLEAF/CLEAF row copies
    {
        const int mloc = tid >> 3;      // 0..63
        const int p8   = tid & 7;
        const int node = 32767 + 64 * b + mloc;
        const int ty = nt[node];
        if (ty != 1 && ty != 2) {
            *(s8v*)(&hD[mloc][p8 * 16])     = *(const s8v*)(HLEAF + (size_t)ty * 128 + p8 * 16);
            *(s8v*)(&hD[mloc][p8 * 16 + 8]) = *(const s8v*)(HLEAF + (size_t)ty * 128 + p8 * 16 + 8);
            if (!(mloc & 1)) {
                const float* cr = CLEAF + (size_t)ty * 128 + p8 * 16;
                #pragma unroll
                for (int q = 0; q < 16; ++q) cD[mloc >> 1][p8 * 16 + q] = cr[q];
            }
        } else {
            const float corr = na[node] - ((ty == 1) ? e1 : e2);
            #pragma unroll
            for (int q = 0; q < 16; ++q) {
                const int jj = p8 * 16 + q;
                const float4 px = PX4[(size_t)ty * 128 + jj];
                const float4 wc = Wcol4[jj];
                const float gi = px.x + corr * wc.x;
                const float gg = px.z + corr * wc.z;
                const float go = px.w + corr * wc.w;
                const float cn = sigf(gi) * tanh_fast(gg);
                const float hn = sigf(go) * tanh_fast(cn);
                hD[mloc][jj] = f2bf(hn);
                if (!(mloc & 1)) cD[mloc >> 1][jj] = cn;
            }
        }
    }
    __syncthreads();
    gemm32_l<1>(32 * b, 32, 16383, nt, na, hD, cD, Bpack, PX4, Wcol4, e1, e2,
                nullptr, nullptr, hM, cM, nullptr);            // L14
    __syncthreads();
    gemm32_l<1>(16 * b, 16, 8191, nt, na, hM, cM, Bpack, PX4, Wcol4, e1, e2,
                nullptr, nullptr, hD, cD, nullptr);            // L13
    __syncthreads();
    gemm32_l<1>(8 * b, 8, 4095, nt, na, hD, cD, Bpack, PX4, Wcol4, e1, e2,
                nullptr, nullptr, hM, cM, nullptr);            // L12
    __syncthreads();
    gemm32_l<0>(4 * b, 4, 2047, nt, na, hM, cM, Bpack, PX4, Wcol4, e1, e2,
                h_out, c_out, nullptr, nullptr, nullptr);      // L11 -> global
}

// ---------------- mega2: levels 10..6 per block ----------------
__global__ __launch_bounds__(512) void mega2(
    const int* __restrict__ nt, const float* __restrict__ na,
    const float* __restrict__ emb,
    const ushort* __restrict__ Bpack, const float4* __restrict__ PX4,
    const float4* __restrict__ Wcol4,
    const ushort* __restrict__ h_in, const float* __restrict__ c_in,   // level-11
    ushort* __restrict__ h_out, float* __restrict__ c_out)             // level-6
{
    __shared__ __align__(16) ushort hD[64][136];
    __shared__ float cD[32][132];
    __shared__ __align__(16) ushort hM[32][136];
    __shared__ float cM[16][132];

    const int b = blockIdx.x;
    const float e1 = emb[255], e2 = emb[383];

    gemm64_g(64 * b, 1024, 1023, nt, na, h_in, c_in,
             Bpack, PX4, Wcol4, e1, e2, hD, cD);               // L10
    __syncthreads();
    gemm32_l<1>(32 * b, 32, 511, nt, na, hD, cD, Bpack, PX4, Wcol4, e1, e2,
                nullptr, nullptr, hM, cM, nullptr);            // L9
    __syncthreads();
    gemm32_l<1>(16 * b, 16, 255, nt, na, hM, cM, Bpack, PX4, Wcol4, e1, e2,
                nullptr, nullptr, hD, cD, nullptr);            // L8
    __syncthreads();
    gemm32_l<1>(8 * b, 8, 127, nt, na, hD, cD, Bpack, PX4, Wcol4, e1, e2,
                nullptr, nullptr, hM, cM, nullptr);            // L7
    __syncthreads();
    gemm32_l<0>(4 * b, 4, 63, nt, na, hM, cM, Bpack, PX4, Wcol4, e1, e2,
                h_out, c_out, nullptr, nullptr, nullptr);      // L6 -> global
}

// ---------------- mega3: levels 5..0 + MLP head, one block ----------------
__global__ __launch_bounds__(512) void mega3(
    const int* __restrict__ nt, const float* __restrict__ na,
    const float* __restrict__ emb,
    const ushort* __restrict__ Bpack, const float4* __restrict__ PX4,
    const float4* __restrict__ Wcol4,
    const ushort* __restrict__ h_in, const float* __restrict__ c_in,   // level-6
    const float* __restrict__ W1, const float* __restrict__ b1,
    const float* __restrict__ W2, const float* __restrict__ b2,
    const float* __restrict__ vmask, float* __restrict__ out)
{
    __shared__ __align__(16) ushort hD[64][136];
    __shared__ float cD[32][132];
    __shared__ __align__(16) ushort hM[32][136];
    __shared__ float cM[16][132];
    __shared__ float hs[128];
    __shared__ float as[128];

    const int tid = threadIdx.x;
    const float e1 = emb[255], e2 = emb[383];

    gemm64_g(0, 32, 31, nt, na, h_in, c_in,
             Bpack, PX4, Wcol4, e1, e2, hD, cD);               // L5 (32 rows)
    __syncthreads();
    gemm32_l<1>(0, 16, 15, nt, na, hD, cD, Bpack, PX4, Wcol4, e1, e2,
                nullptr, nullptr, hM, cM, nullptr);            // L4
    __syncthreads();
    gemm32_l<1>(0, 8, 7, nt, na, hM, cM, Bpack, PX4, Wcol4, e1, e2,
                nullptr, nullptr, hD, cD, nullptr);            // L3
    __syncthreads();
    gemm32_l<1>(0, 4, 3, nt, na, hD, cD, Bpack, PX4, Wcol4, e1, e2,
                nullptr, nullptr, hM, cM, nullptr);            // L2
    __syncthreads();
    gemm32_l<1>(0, 2, 1, nt, na, hM, cM, Bpack, PX4, Wcol4, e1, e2,
                nullptr, nullptr, hD, cD, nullptr);            // L1
    __syncthreads();
    gemm32_l<2>(0, 1, 0, nt, na, hD, cD, Bpack, PX4, Wcol4, e1, e2,
                nullptr, nullptr, nullptr, nullptr, hs);       // L0 -> hs
    __syncthreads();
    // head
    if (tid < 128) {
        float a1h = b1[tid];
        #pragma unroll 4
        for (int k = 0; k < 128; ++k) a1h = fmaf(hs[k], W1[tid * 128 + k], a1h);
        as[tid] = fmaxf(a1h, 0.0f);
    }
    __syncthreads();
    if (tid < 32) {
        float l = b2[tid];
        #pragma unroll 4
        for (int k = 0; k < 128; ++k) l = fmaf(as[k], W2[tid * 128 + k], l);
        l = (l + logf(vmask[tid])) * (1.0f / 3.0f);
        float mx = l;
        #pragma unroll
        for (int o = 16; o >= 1; o >>= 1) mx = fmaxf(mx, __shfl_xor(mx, o, 32));
        const float e = __expf(l - mx);
        float s = e;
        #pragma unroll
        for (int o = 16; o >= 1; o >>= 1) s += __shfl_xor(s, o, 32);
        out[tid] = e / s;
    }
}

extern "C" void kernel_launch(void* const* d_in, const int* in_sizes, int n_in,
                              void* d_out, int out_size, void* d_ws, size_t ws_size,
                              hipStream_t stream)
{
    const int*   node_types = (const int*)  d_in[0];
    const float* node_args  = (const float*)d_in[1];
    const float* vmask      = (const float*)d_in[2];
    const float* emb        = (const float*)d_in[3];
    const float* Wih        = (const float*)d_in[4];
    const float* Whh        = (const float*)d_in[5];
    const float* bih        = (const float*)d_in[6];
    const float* bhh        = (const float*)d_in[7];
    const float* W1         = (const float*)d_in[8];
    const float* b1         = (const float*)d_in[9];
    const float* W2         = (const float*)d_in[10];
    const float* b2         = (const float*)d_in[11];

    char* w = (char*)d_ws;
    ushort* Bpack = (ushort*)(w);                 // 16384*8*2  = 262,144
    float4* PX4   = (float4*)(w + 262144);        // 16384*16   = 262,144
    float4* Wcol4 = (float4*)(w + 524288);        // 128*16     =   2,048
    ushort* HLEAF = (ushort*)(w + 526336);        // 16384*2    =  32,768
    float*  CLEAF = (float*) (w + 559104);        // 16384*4    =  65,536
    ushort* h11   = (ushort*)(w + 624640);        // 2048*128*2 = 524,288
    float*  c11   = (float*) (w + 1148928);       // 1024*128*4 = 524,288
    ushort* h6    = (ushort*)(w + 1673216);       // 64*128*2   =  16,384
    float*  c6    = (float*) (w + 1689600);       // 32*128*4   =  16,384

    float* out = (float*)d_out;

    prepass<<<128, 256, 0, stream>>>(emb, Wih, Whh, bih, bhh,
                                     Bpack, PX4, Wcol4, HLEAF, CLEAF);
    mega1<<<512, 512, 0, stream>>>(node_types, node_args, emb,
                                   Bpack, PX4, Wcol4, HLEAF, CLEAF, h11, c11);
    mega2<<<16, 512, 0, stream>>>(node_types, node_args, emb,
                                  Bpack, PX4, Wcol4, h11, c11, h6, c6);
    mega3<<<1, 512, 0, stream>>>(node_types, node_args, emb,
                                 Bpack, PX4, Wcol4, h6, c6,
                                 W1, b1, W2, b2, vmask, out);
}